// Round 8
// baseline (337.803 us; speedup 1.0000x reference)
//
#include <hip/hip_runtime.h>

#define BB 8
#define CCH 19
#define HH 512
#define WW 1024
#define HW (HH * WW)          // 524288
#define NPIX (BB * HW)        // 4194304
#define CHW (CCH * HW)
#define N4 (NPIX / 4)         // 1048576
#define GRID 1024
#define BLOCK 256
// N4 == GRID*BLOCK*4 exactly

#define FIX_SCALE 17179869184.0   // 2^34

typedef float f32x4 __attribute__((ext_vector_type(4)));

struct SelState {
    unsigned b1, k1;
};

__device__ __forceinline__ unsigned fkey(float x) {
    unsigned u = __float_as_uint(x);
    return (u & 0x80000000u) ? ~u : (u | 0x80000000u);
}
// two's-complement fixed point; |total| < 4.2M * 20 * 2^34 < 2^63
__device__ __forceinline__ unsigned long long fix64(float x) {
    return (unsigned long long)(long long)((double)x * FIX_SCALE);
}
__device__ __forceinline__ unsigned agent_load_u32(const unsigned* p) {
    return __hip_atomic_load(p, __ATOMIC_RELAXED, __HIP_MEMORY_SCOPE_AGENT);
}
__device__ __forceinline__ unsigned long long agent_load_u64(const unsigned long long* p) {
    return __hip_atomic_load(p, __ATOMIC_RELAXED, __HIP_MEMORY_SCOPE_AGENT);
}

// ---- k1: CE loss + 11-bit histogram; last block scans h1 -> st ----
// Loop body is the round-2/3 version VERBATIM: the fmax chain gives every
// v[c] two uses (fmax + exp), forcing all 19 channel loads live at once ->
// compiler clusters them (MLP=19). Rounds 4-7 dropped max-sub; single-use
// v[c] let the compiler sink loads into the exp loop (VGPR=44, serial
// latency chain, 287us @ 573 GB/s). Expect VGPR ~110+ here: that is the
// signature that the schedule is right.
__global__ __launch_bounds__(BLOCK) void k1_loss_hist(
    const float* __restrict__ pred, const int* __restrict__ target,
    const int* __restrict__ step_p, float* __restrict__ loss,
    unsigned* __restrict__ h1, SelState* __restrict__ st,
    unsigned* __restrict__ ticket)
{
    __shared__ unsigned h[2048];
    __shared__ unsigned chunk[256];
    __shared__ unsigned isLast;
    const int tid = threadIdx.x, bid = blockIdx.x;

    for (int i = tid; i < 2048; i += BLOCK) h[i] = 0u;
    __syncthreads();

#pragma unroll
    for (int it = 0; it < 4; ++it) {
        const int i4 = (bid * BLOCK + tid) + it * (GRID * BLOCK);
        const int p0 = i4 << 2;
        const int b = p0 >> 19;          // / HW
        const int hw = p0 & (HW - 1);
        const float* base = pred + (size_t)b * CHW + hw;

        float4 v[CCH];
#pragma unroll
        for (int c = 0; c < CCH; ++c)
            v[c] = *reinterpret_cast<const float4*>(base + (size_t)c * HW);
        const int4 tg = *reinterpret_cast<const int4*>(target + p0);

        float4 mx = v[0];
#pragma unroll
        for (int c = 1; c < CCH; ++c) {
            mx.x = fmaxf(mx.x, v[c].x);
            mx.y = fmaxf(mx.y, v[c].y);
            mx.z = fmaxf(mx.z, v[c].z);
            mx.w = fmaxf(mx.w, v[c].w);
        }
        float4 s = make_float4(0.f, 0.f, 0.f, 0.f);
        float4 xt = make_float4(0.f, 0.f, 0.f, 0.f);
#pragma unroll
        for (int c = 0; c < CCH; ++c) {
            s.x += __expf(v[c].x - mx.x);
            s.y += __expf(v[c].y - mx.y);
            s.z += __expf(v[c].z - mx.z);
            s.w += __expf(v[c].w - mx.w);
            xt.x = (tg.x == c) ? v[c].x : xt.x;
            xt.y = (tg.y == c) ? v[c].y : xt.y;
            xt.z = (tg.z == c) ? v[c].z : xt.z;
            xt.w = (tg.w == c) ? v[c].w : xt.w;
        }
        float4 o;
        o.x = __logf(s.x) + mx.x - xt.x;
        o.y = __logf(s.y) + mx.y - xt.y;
        o.z = __logf(s.z) + mx.z - xt.z;
        o.w = __logf(s.w) + mx.w - xt.w;
        *reinterpret_cast<float4*>(loss + p0) = o;

        atomicAdd(&h[fkey(o.x) >> 21], 1u);
        atomicAdd(&h[fkey(o.y) >> 21], 1u);
        atomicAdd(&h[fkey(o.z) >> 21], 1u);
        atomicAdd(&h[fkey(o.w) >> 21], 1u);
    }
    __syncthreads();
    for (int i = tid; i < 2048; i += BLOCK) {
        unsigned c = h[i];
        if (c) atomicAdd(&h1[i], c);
    }
    __threadfence();
    if (tid == 0) isLast = (atomicAdd(ticket, 1u) == GRID - 1) ? 1u : 0u;
    __syncthreads();
    if (!isLast) return;

    // ---- last block: suffix-scan h1, find b1/k1 ----
    unsigned num;
    {
        int s = step_p[0];
        double m = pow(0.99998, (double)s);
        double f = m > 0.15 ? m : 0.15;
        num = (unsigned)(0.15 * (double)BB * (double)HH * (double)WW * f);
    }
    unsigned local[8];
    unsigned lsum = 0;
#pragma unroll
    for (int j = 0; j < 8; ++j) { local[j] = agent_load_u32(&h1[tid * 8 + j]); lsum += local[j]; }
    chunk[tid] = lsum;
    __syncthreads();
    for (int off = 1; off < 256; off <<= 1) {
        unsigned add = (tid + off < 256) ? chunk[tid + off] : 0u;
        __syncthreads();
        chunk[tid] += add;
        __syncthreads();
    }
    unsigned cum = (tid < 255) ? chunk[tid + 1] : 0u;   // strictly above my chunk
#pragma unroll
    for (int j = 7; j >= 0; --j) {
        unsigned c = local[j];
        if (num > cum && num <= cum + c) {
            st->b1 = (unsigned)(tid * 8 + j);
            st->k1 = num - cum;
        }
        cum += c;
    }
}

// ---- k2: selective pass over loss; last block finalizes ----
__global__ __launch_bounds__(BLOCK) void k2_select(
    const float* __restrict__ loss, const SelState* __restrict__ st,
    unsigned* __restrict__ h2, unsigned long long* __restrict__ bs2,
    unsigned long long* __restrict__ aboveSum, unsigned* __restrict__ aboveCnt,
    unsigned* __restrict__ ticket, float* __restrict__ out)
{
    __shared__ unsigned h[2048];
    __shared__ unsigned long long bs[2048];
    __shared__ unsigned chunk[256];
    __shared__ unsigned b_sh, isLast;
    __shared__ unsigned long long wsum[4];
    __shared__ unsigned wcnt[4];
    const int tid = threadIdx.x, bid = blockIdx.x;

    for (int i = tid; i < 2048; i += BLOCK) { h[i] = 0u; bs[i] = 0ull; }
    __syncthreads();

    const unsigned b1 = st->b1;
    unsigned long long asum = 0ull;
    unsigned acnt = 0;
#pragma unroll
    for (int it = 0; it < 4; ++it) {
        const int i4 = (bid * BLOCK + tid) + it * (GRID * BLOCK);
        const f32x4 v = reinterpret_cast<const f32x4*>(loss)[i4];
        unsigned u, hi;
        u = fkey(v.x); hi = u >> 21;
        if (hi > b1) { asum += fix64(v.x); acnt++; }
        else if (hi == b1) { unsigned idx = (u >> 10) & 2047u; atomicAdd(&h[idx], 1u); atomicAdd(&bs[idx], fix64(v.x)); }
        u = fkey(v.y); hi = u >> 21;
        if (hi > b1) { asum += fix64(v.y); acnt++; }
        else if (hi == b1) { unsigned idx = (u >> 10) & 2047u; atomicAdd(&h[idx], 1u); atomicAdd(&bs[idx], fix64(v.y)); }
        u = fkey(v.z); hi = u >> 21;
        if (hi > b1) { asum += fix64(v.z); acnt++; }
        else if (hi == b1) { unsigned idx = (u >> 10) & 2047u; atomicAdd(&h[idx], 1u); atomicAdd(&bs[idx], fix64(v.z)); }
        u = fkey(v.w); hi = u >> 21;
        if (hi > b1) { asum += fix64(v.w); acnt++; }
        else if (hi == b1) { unsigned idx = (u >> 10) & 2047u; atomicAdd(&h[idx], 1u); atomicAdd(&bs[idx], fix64(v.w)); }
    }
    // deterministic integer block reduction of the "above" partials
#pragma unroll
    for (int off = 32; off >= 1; off >>= 1) {
        asum += __shfl_down(asum, off);
        acnt += __shfl_down(acnt, off);
    }
    {
        const int wid = tid >> 6, lane = tid & 63;
        if (lane == 0) { wsum[wid] = asum; wcnt[wid] = acnt; }
    }
    __syncthreads();
    if (tid == 0) {
        unsigned long long ts = wsum[0] + wsum[1] + wsum[2] + wsum[3];
        unsigned tc = wcnt[0] + wcnt[1] + wcnt[2] + wcnt[3];
        if (ts) atomicAdd(aboveSum, ts);
        if (tc) atomicAdd(aboveCnt, tc);
    }
    __syncthreads();
    for (int i = tid; i < 2048; i += BLOCK) {
        unsigned c = h[i];
        if (c) { atomicAdd(&h2[i], c); atomicAdd(&bs2[i], bs[i]); }
    }
    __threadfence();
    if (tid == 0) isLast = (atomicAdd(ticket, 1u) == GRID - 1) ? 1u : 0u;
    __syncthreads();
    if (!isLast) return;

    // ---- last block: scan h2, include bins >= b2, add above partials ----
    const unsigned k1 = st->k1;
    if (tid == 0) b_sh = 0u;    // fallback: whole b1 bin
    unsigned local[8];
    unsigned lsum = 0;
#pragma unroll
    for (int j = 0; j < 8; ++j) { local[j] = agent_load_u32(&h2[tid * 8 + j]); lsum += local[j]; }
    chunk[tid] = lsum;
    __syncthreads();
    for (int off = 1; off < 256; off <<= 1) {
        unsigned add = (tid + off < 256) ? chunk[tid + off] : 0u;
        __syncthreads();
        chunk[tid] += add;
        __syncthreads();
    }
    {
        unsigned cum = (tid < 255) ? chunk[tid + 1] : 0u;
#pragma unroll
        for (int j = 7; j >= 0; --j) {
            unsigned c = local[j];
            if (k1 > cum && k1 <= cum + c) b_sh = (unsigned)(tid * 8 + j);
            cum += c;
        }
    }
    __syncthreads();
    const unsigned b2 = b_sh;

    unsigned long long s = 0ull;
    unsigned cnt = 0;
#pragma unroll
    for (int j = 0; j < 8; ++j) {
        const unsigned bin = (unsigned)(tid * 8 + j);
        if (bin >= b2) { s += agent_load_u64(&bs2[bin]); cnt += local[j]; }
    }
#pragma unroll
    for (int off = 32; off >= 1; off >>= 1) {
        s += __shfl_down(s, off);
        cnt += __shfl_down(cnt, off);
    }
    {
        const int wid = tid >> 6, lane = tid & 63;
        if (lane == 0) { wsum[wid] = s; wcnt[wid] = cnt; }
    }
    __syncthreads();
    if (tid == 0) {
        unsigned long long ts = wsum[0] + wsum[1] + wsum[2] + wsum[3] + agent_load_u64(aboveSum);
        unsigned long long tc = (unsigned long long)(wcnt[0] + wcnt[1] + wcnt[2] + wcnt[3])
                              + (unsigned long long)agent_load_u32(aboveCnt);
        out[0] = (float)(((double)(long long)ts / FIX_SCALE) / (double)tc);
    }
}

extern "C" void kernel_launch(void* const* d_in, const int* in_sizes, int n_in,
                              void* d_out, int out_size, void* d_ws, size_t ws_size,
                              hipStream_t stream) {
    const float* pred = (const float*)d_in[0];
    const int* target = (const int*)d_in[1];
    const int* step = (const int*)d_in[2];
    float* out = (float*)d_out;

    char* ws = (char*)d_ws;
    const size_t LOSS_BYTES = (size_t)NPIX * 4;   // 16 MiB
    float* loss = (float*)ws;
    char* sb = ws + LOSS_BYTES;
    // zeroed state (contiguous):
    unsigned* h1 = (unsigned*)(sb);                               // 8192 B
    unsigned* h2 = (unsigned*)(sb + 8192);                        // 8192 B
    unsigned long long* bs2 = (unsigned long long*)(sb + 16384);  // 16384 B
    unsigned long long* aboveSum = (unsigned long long*)(sb + 32768);  // 8 B
    unsigned* aboveCnt = (unsigned*)(sb + 32776);                 // 4 B
    unsigned* ticket1 = (unsigned*)(sb + 32780);                  // 4 B
    unsigned* ticket2 = (unsigned*)(sb + 32784);                  // 4 B
    // not zeroed (fully rewritten):
    SelState* st = (SelState*)(sb + 32792);

    hipMemsetAsync(sb, 0, 32788, stream);
    k1_loss_hist<<<GRID, BLOCK, 0, stream>>>(pred, target, step, loss, h1, st, ticket1);
    k2_select<<<GRID, BLOCK, 0, stream>>>(loss, st, h2, bs2, aboveSum, aboveCnt, ticket2, out);
}

// Round 9
// 337.507 us; speedup vs baseline: 1.0009x; 1.0009x over previous
//
#include <hip/hip_runtime.h>

#define BB 8
#define CCH 19
#define HH 512
#define WW 1024
#define HW (HH * WW)          // 524288
#define NPIX (BB * HW)        // 4194304
#define CHW (CCH * HW)
#define N4 (NPIX / 4)         // 1048576
#define GRID 1024
#define BLOCK 256

#define FIX_SCALE 17179869184.0   // 2^34

typedef float f32x4 __attribute__((ext_vector_type(4)));

struct SelState {
    unsigned b1, k1;
};

__device__ __forceinline__ unsigned fkey(float x) {
    unsigned u = __float_as_uint(x);
    return (u & 0x80000000u) ? ~u : (u | 0x80000000u);
}
// two's-complement fixed point; |total| < 4.2M * 20 * 2^34 < 2^63
__device__ __forceinline__ unsigned long long fix64(float x) {
    return (unsigned long long)(long long)((double)x * FIX_SCALE);
}
__device__ __forceinline__ unsigned agent_load_u32(const unsigned* p) {
    return __hip_atomic_load(p, __ATOMIC_RELAXED, __HIP_MEMORY_SCOPE_AGENT);
}
__device__ __forceinline__ unsigned long long agent_load_u64(const unsigned long long* p) {
    return __hip_atomic_load(p, __ATOMIC_RELAXED, __HIP_MEMORY_SCOPE_AGENT);
}

// ---- k1: CE loss + 11-bit histogram; last block scans h1 -> st ----
// LOOP MUST BE RUNTIME GRID-STRIDE (gridDim.x), NOT #pragma-unrolled:
// rounds 5-8 unrolled it<4 at compile time -> compiler sank the 19 channel
// loads into their consumers to cap VGPR (44-56), serializing on memory
// latency (287us, 570 GB/s, VALUBusy 6%). The runtime-stride form (rounds
// 2/3, ~95us) emits all 19 global_load_dwordx4 back-to-back per iteration
// (MLP=19, VGPR>=100). Success signature: VGPR_Count >= 100.
__global__ __launch_bounds__(BLOCK) void k1_loss_hist(
    const float* __restrict__ pred, const int* __restrict__ target,
    const int* __restrict__ step_p, float* __restrict__ loss,
    unsigned* __restrict__ h1, SelState* __restrict__ st,
    unsigned* __restrict__ ticket)
{
    __shared__ unsigned h[2048];
    __shared__ unsigned chunk[256];
    __shared__ unsigned isLast;
    const int tid = threadIdx.x, bid = blockIdx.x;

    for (int i = tid; i < 2048; i += BLOCK) h[i] = 0u;
    __syncthreads();

    int stride = gridDim.x * BLOCK;   // runtime value: prevents unrolling
    for (int i4 = bid * BLOCK + tid; i4 < N4; i4 += stride) {
        const int p0 = i4 << 2;
        const int b = p0 >> 19;          // / HW
        const int hw = p0 & (HW - 1);
        const float* base = pred + (size_t)b * CHW + hw;

        float4 v[CCH];
#pragma unroll
        for (int c = 0; c < CCH; ++c)
            v[c] = *reinterpret_cast<const float4*>(base + (size_t)c * HW);
        const int4 tg = *reinterpret_cast<const int4*>(target + p0);

        float4 mx = v[0];
#pragma unroll
        for (int c = 1; c < CCH; ++c) {
            mx.x = fmaxf(mx.x, v[c].x);
            mx.y = fmaxf(mx.y, v[c].y);
            mx.z = fmaxf(mx.z, v[c].z);
            mx.w = fmaxf(mx.w, v[c].w);
        }
        float4 s = make_float4(0.f, 0.f, 0.f, 0.f);
        float4 xt = make_float4(0.f, 0.f, 0.f, 0.f);
#pragma unroll
        for (int c = 0; c < CCH; ++c) {
            s.x += __expf(v[c].x - mx.x);
            s.y += __expf(v[c].y - mx.y);
            s.z += __expf(v[c].z - mx.z);
            s.w += __expf(v[c].w - mx.w);
            xt.x = (tg.x == c) ? v[c].x : xt.x;
            xt.y = (tg.y == c) ? v[c].y : xt.y;
            xt.z = (tg.z == c) ? v[c].z : xt.z;
            xt.w = (tg.w == c) ? v[c].w : xt.w;
        }
        float4 o;
        o.x = __logf(s.x) + mx.x - xt.x;
        o.y = __logf(s.y) + mx.y - xt.y;
        o.z = __logf(s.z) + mx.z - xt.z;
        o.w = __logf(s.w) + mx.w - xt.w;
        *reinterpret_cast<float4*>(loss + p0) = o;

        atomicAdd(&h[fkey(o.x) >> 21], 1u);
        atomicAdd(&h[fkey(o.y) >> 21], 1u);
        atomicAdd(&h[fkey(o.z) >> 21], 1u);
        atomicAdd(&h[fkey(o.w) >> 21], 1u);
    }
    __syncthreads();
    for (int i = tid; i < 2048; i += BLOCK) {
        unsigned c = h[i];
        if (c) atomicAdd(&h1[i], c);
    }
    __threadfence();
    if (tid == 0) isLast = (atomicAdd(ticket, 1u) == GRID - 1) ? 1u : 0u;
    __syncthreads();
    if (!isLast) return;

    // ---- last block: suffix-scan h1, find b1/k1 ----
    unsigned num;
    {
        int s = step_p[0];
        double m = pow(0.99998, (double)s);
        double f = m > 0.15 ? m : 0.15;
        num = (unsigned)(0.15 * (double)BB * (double)HH * (double)WW * f);
    }
    unsigned local[8];
    unsigned lsum = 0;
#pragma unroll
    for (int j = 0; j < 8; ++j) { local[j] = agent_load_u32(&h1[tid * 8 + j]); lsum += local[j]; }
    chunk[tid] = lsum;
    __syncthreads();
    for (int off = 1; off < 256; off <<= 1) {
        unsigned add = (tid + off < 256) ? chunk[tid + off] : 0u;
        __syncthreads();
        chunk[tid] += add;
        __syncthreads();
    }
    unsigned cum = (tid < 255) ? chunk[tid + 1] : 0u;   // strictly above my chunk
#pragma unroll
    for (int j = 7; j >= 0; --j) {
        unsigned c = local[j];
        if (num > cum && num <= cum + c) {
            st->b1 = (unsigned)(tid * 8 + j);
            st->k1 = num - cum;
        }
        cum += c;
    }
}

// ---- k2: selective pass over loss; last block finalizes ----
__global__ __launch_bounds__(BLOCK) void k2_select(
    const float* __restrict__ loss, const SelState* __restrict__ st,
    unsigned* __restrict__ h2, unsigned long long* __restrict__ bs2,
    unsigned long long* __restrict__ aboveSum, unsigned* __restrict__ aboveCnt,
    unsigned* __restrict__ ticket, float* __restrict__ out)
{
    __shared__ unsigned h[2048];
    __shared__ unsigned long long bs[2048];
    __shared__ unsigned chunk[256];
    __shared__ unsigned b_sh, isLast;
    __shared__ unsigned long long wsum[4];
    __shared__ unsigned wcnt[4];
    const int tid = threadIdx.x, bid = blockIdx.x;

    for (int i = tid; i < 2048; i += BLOCK) { h[i] = 0u; bs[i] = 0ull; }
    __syncthreads();

    const unsigned b1 = st->b1;
    unsigned long long asum = 0ull;
    unsigned acnt = 0;
    int stride = gridDim.x * BLOCK;   // runtime grid-stride (see k1 comment)
    for (int i4 = bid * BLOCK + tid; i4 < N4; i4 += stride) {
        const f32x4 v = reinterpret_cast<const f32x4*>(loss)[i4];
        unsigned u, hi;
        u = fkey(v.x); hi = u >> 21;
        if (hi > b1) { asum += fix64(v.x); acnt++; }
        else if (hi == b1) { unsigned idx = (u >> 10) & 2047u; atomicAdd(&h[idx], 1u); atomicAdd(&bs[idx], fix64(v.x)); }
        u = fkey(v.y); hi = u >> 21;
        if (hi > b1) { asum += fix64(v.y); acnt++; }
        else if (hi == b1) { unsigned idx = (u >> 10) & 2047u; atomicAdd(&h[idx], 1u); atomicAdd(&bs[idx], fix64(v.y)); }
        u = fkey(v.z); hi = u >> 21;
        if (hi > b1) { asum += fix64(v.z); acnt++; }
        else if (hi == b1) { unsigned idx = (u >> 10) & 2047u; atomicAdd(&h[idx], 1u); atomicAdd(&bs[idx], fix64(v.z)); }
        u = fkey(v.w); hi = u >> 21;
        if (hi > b1) { asum += fix64(v.w); acnt++; }
        else if (hi == b1) { unsigned idx = (u >> 10) & 2047u; atomicAdd(&h[idx], 1u); atomicAdd(&bs[idx], fix64(v.w)); }
    }
    // deterministic integer block reduction of the "above" partials
#pragma unroll
    for (int off = 32; off >= 1; off >>= 1) {
        asum += __shfl_down(asum, off);
        acnt += __shfl_down(acnt, off);
    }
    {
        const int wid = tid >> 6, lane = tid & 63;
        if (lane == 0) { wsum[wid] = asum; wcnt[wid] = acnt; }
    }
    __syncthreads();
    if (tid == 0) {
        unsigned long long ts = wsum[0] + wsum[1] + wsum[2] + wsum[3];
        unsigned tc = wcnt[0] + wcnt[1] + wcnt[2] + wcnt[3];
        if (ts) atomicAdd(aboveSum, ts);
        if (tc) atomicAdd(aboveCnt, tc);
    }
    __syncthreads();
    for (int i = tid; i < 2048; i += BLOCK) {
        unsigned c = h[i];
        if (c) { atomicAdd(&h2[i], c); atomicAdd(&bs2[i], bs[i]); }
    }
    __threadfence();
    if (tid == 0) isLast = (atomicAdd(ticket, 1u) == GRID - 1) ? 1u : 0u;
    __syncthreads();
    if (!isLast) return;

    // ---- last block: scan h2, include bins >= b2, add above partials ----
    const unsigned k1 = st->k1;
    if (tid == 0) b_sh = 0u;    // fallback: whole b1 bin
    unsigned local[8];
    unsigned lsum = 0;
#pragma unroll
    for (int j = 0; j < 8; ++j) { local[j] = agent_load_u32(&h2[tid * 8 + j]); lsum += local[j]; }
    chunk[tid] = lsum;
    __syncthreads();
    for (int off = 1; off < 256; off <<= 1) {
        unsigned add = (tid + off < 256) ? chunk[tid + off] : 0u;
        __syncthreads();
        chunk[tid] += add;
        __syncthreads();
    }
    {
        unsigned cum = (tid < 255) ? chunk[tid + 1] : 0u;
#pragma unroll
        for (int j = 7; j >= 0; --j) {
            unsigned c = local[j];
            if (k1 > cum && k1 <= cum + c) b_sh = (unsigned)(tid * 8 + j);
            cum += c;
        }
    }
    __syncthreads();
    const unsigned b2 = b_sh;

    unsigned long long s = 0ull;
    unsigned cnt = 0;
#pragma unroll
    for (int j = 0; j < 8; ++j) {
        const unsigned bin = (unsigned)(tid * 8 + j);
        if (bin >= b2) { s += agent_load_u64(&bs2[bin]); cnt += local[j]; }
    }
#pragma unroll
    for (int off = 32; off >= 1; off >>= 1) {
        s += __shfl_down(s, off);
        cnt += __shfl_down(cnt, off);
    }
    {
        const int wid = tid >> 6, lane = tid & 63;
        if (lane == 0) { wsum[wid] = s; wcnt[wid] = cnt; }
    }
    __syncthreads();
    if (tid == 0) {
        unsigned long long ts = wsum[0] + wsum[1] + wsum[2] + wsum[3] + agent_load_u64(aboveSum);
        unsigned long long tc = (unsigned long long)(wcnt[0] + wcnt[1] + wcnt[2] + wcnt[3])
                              + (unsigned long long)agent_load_u32(aboveCnt);
        out[0] = (float)(((double)(long long)ts / FIX_SCALE) / (double)tc);
    }
}

extern "C" void kernel_launch(void* const* d_in, const int* in_sizes, int n_in,
                              void* d_out, int out_size, void* d_ws, size_t ws_size,
                              hipStream_t stream) {
    const float* pred = (const float*)d_in[0];
    const int* target = (const int*)d_in[1];
    const int* step = (const int*)d_in[2];
    float* out = (float*)d_out;

    char* ws = (char*)d_ws;
    const size_t LOSS_BYTES = (size_t)NPIX * 4;   // 16 MiB
    float* loss = (float*)ws;
    char* sb = ws + LOSS_BYTES;
    // zeroed state (contiguous):
    unsigned* h1 = (unsigned*)(sb);                               // 8192 B
    unsigned* h2 = (unsigned*)(sb + 8192);                        // 8192 B
    unsigned long long* bs2 = (unsigned long long*)(sb + 16384);  // 16384 B
    unsigned long long* aboveSum = (unsigned long long*)(sb + 32768);  // 8 B
    unsigned* aboveCnt = (unsigned*)(sb + 32776);                 // 4 B
    unsigned* ticket1 = (unsigned*)(sb + 32780);                  // 4 B
    unsigned* ticket2 = (unsigned*)(sb + 32784);                  // 4 B
    // not zeroed (fully rewritten):
    SelState* st = (SelState*)(sb + 32792);

    hipMemsetAsync(sb, 0, 32788, stream);
    k1_loss_hist<<<GRID, BLOCK, 0, stream>>>(pred, target, step, loss, h1, st, ticket1);
    k2_select<<<GRID, BLOCK, 0, stream>>>(loss, st, h2, bs2, aboveSum, aboveCnt, ticket2, out);
}

// Round 10
// 118.264 us; speedup vs baseline: 2.8564x; 2.8539x over previous
//
#include <hip/hip_runtime.h>

#define BB 8
#define CCH 19
#define HH 512
#define WW 1024
#define HW (HH * WW)          // 524288
#define NPIX (BB * HW)        // 4194304
#define CHW (CCH * HW)
#define N4 (NPIX / 4)         // 1048576

#define FIX_SCALE 17179869184.0   // 2^34

struct SelState {
    unsigned b1, k1;
};

__device__ __forceinline__ unsigned fkey(float x) {
    unsigned u = __float_as_uint(x);
    return (u & 0x80000000u) ? ~u : (u | 0x80000000u);
}
// two's-complement fixed point; |total| < 4.2M * 20 * 2^34 < 2^63
__device__ __forceinline__ unsigned long long fix64(float x) {
    return (unsigned long long)(long long)((double)x * FIX_SCALE);
}

// ---- pass 1: per-pixel CE (float4) + fused 11-bit count histogram ----
// KEEP THIS FUNCTION CLEAN: no pow(), no scan tail, no ticket, no extra
// LDS. Rounds 5-9 fused a last-block tail (pow + scan) into this function
// and the scheduler compressed the loop to VGPR~60 -> ~10 loads in flight
// -> 290us @ 600 GB/s (3x slower). As a clean function (rounds 2/3) the
// scheduler keeps all 19 channel loads in flight (VGPR~110) -> <90us.
__global__ __launch_bounds__(256) void k_loss_hist(const float* __restrict__ pred,
                                                   const int* __restrict__ target,
                                                   float* __restrict__ loss,
                                                   unsigned* __restrict__ hist) {
    __shared__ unsigned h[2048];
    for (int i = threadIdx.x; i < 2048; i += 256) h[i] = 0;
    __syncthreads();

    int stride = gridDim.x * 256;
    for (int i4 = blockIdx.x * 256 + threadIdx.x; i4 < N4; i4 += stride) {
        int p0 = i4 << 2;
        int b = p0 >> 19;           // / HW
        int hw = p0 & (HW - 1);
        const float* base = pred + (size_t)b * CHW + hw;

        float4 v[CCH];
#pragma unroll
        for (int c = 0; c < CCH; ++c)
            v[c] = *reinterpret_cast<const float4*>(base + (size_t)c * HW);
        int4 tg = *reinterpret_cast<const int4*>(target + p0);

        float4 mx = v[0];
#pragma unroll
        for (int c = 1; c < CCH; ++c) {
            mx.x = fmaxf(mx.x, v[c].x);
            mx.y = fmaxf(mx.y, v[c].y);
            mx.z = fmaxf(mx.z, v[c].z);
            mx.w = fmaxf(mx.w, v[c].w);
        }
        float4 s = make_float4(0.f, 0.f, 0.f, 0.f);
        float4 xt = make_float4(0.f, 0.f, 0.f, 0.f);
#pragma unroll
        for (int c = 0; c < CCH; ++c) {
            s.x += __expf(v[c].x - mx.x);
            s.y += __expf(v[c].y - mx.y);
            s.z += __expf(v[c].z - mx.z);
            s.w += __expf(v[c].w - mx.w);
            xt.x = (tg.x == c) ? v[c].x : xt.x;
            xt.y = (tg.y == c) ? v[c].y : xt.y;
            xt.z = (tg.z == c) ? v[c].z : xt.z;
            xt.w = (tg.w == c) ? v[c].w : xt.w;
        }
        float4 o;
        o.x = __logf(s.x) + mx.x - xt.x;
        o.y = __logf(s.y) + mx.y - xt.y;
        o.z = __logf(s.z) + mx.z - xt.z;
        o.w = __logf(s.w) + mx.w - xt.w;
        *reinterpret_cast<float4*>(loss + p0) = o;

        atomicAdd(&h[fkey(o.x) >> 21], 1u);
        atomicAdd(&h[fkey(o.y) >> 21], 1u);
        atomicAdd(&h[fkey(o.z) >> 21], 1u);
        atomicAdd(&h[fkey(o.w) >> 21], 1u);
    }
    __syncthreads();
    for (int i = threadIdx.x; i < 2048; i += 256) {
        unsigned c = h[i];
        if (c) atomicAdd(&hist[i], c);
    }
}

// ---- suffix-scan over h1 (1 block): compute num from step, find b1/k1 ----
__global__ __launch_bounds__(256) void k_scan1(const int* __restrict__ step_p,
                                               const unsigned* __restrict__ hist,
                                               SelState* st) {
    __shared__ unsigned chunk[256];
    int t = threadIdx.x;
    unsigned k;
    {
        int s = step_p[0];
        double m = pow(0.99998, (double)s);
        double f = m > 0.15 ? m : 0.15;
        k = (unsigned)(0.15 * (double)BB * (double)HH * (double)WW * f);
    }

    unsigned local[8];
    unsigned lsum = 0;
#pragma unroll
    for (int j = 0; j < 8; ++j) { local[j] = hist[t * 8 + j]; lsum += local[j]; }
    chunk[t] = lsum;
    __syncthreads();
    for (int off = 1; off < 256; off <<= 1) {
        unsigned add = (t + off < 256) ? chunk[t + off] : 0u;
        __syncthreads();
        chunk[t] += add;
        __syncthreads();
    }
    unsigned cum = (t < 255) ? chunk[t + 1] : 0u;  // count strictly above my chunk
#pragma unroll
    for (int j = 7; j >= 0; --j) {
        unsigned c = local[j];
        if (k > cum && k <= cum + c) {
            st->b1 = (unsigned)(t * 8 + j);
            st->k1 = k - cum;
        }
        cum += c;
    }
}

// ---- pass 2: above-b1 -> register sum/count; in-b1 -> 11-bit LDS hist ----
__global__ __launch_bounds__(256) void k_hist2(const float* __restrict__ loss,
                                               const SelState* __restrict__ st,
                                               unsigned* __restrict__ h2g,
                                               unsigned long long* __restrict__ bs2g,
                                               unsigned long long* __restrict__ aboveSum,
                                               unsigned* __restrict__ aboveCnt) {
    __shared__ unsigned h[2048];
    __shared__ unsigned long long bs[2048];
    for (int i = threadIdx.x; i < 2048; i += 256) { h[i] = 0; bs[i] = 0ull; }
    __syncthreads();
    unsigned b1 = st->b1;
    unsigned long long asum = 0ull;
    unsigned acnt = 0;
    int stride = gridDim.x * 256;
    for (int i4 = blockIdx.x * 256 + threadIdx.x; i4 < N4; i4 += stride) {
        float4 v = reinterpret_cast<const float4*>(loss)[i4];
        unsigned u, hi;
        u = fkey(v.x); hi = u >> 21;
        if (hi > b1) { asum += fix64(v.x); acnt++; }
        else if (hi == b1) { unsigned idx = (u >> 10) & 2047u; atomicAdd(&h[idx], 1u); atomicAdd(&bs[idx], fix64(v.x)); }
        u = fkey(v.y); hi = u >> 21;
        if (hi > b1) { asum += fix64(v.y); acnt++; }
        else if (hi == b1) { unsigned idx = (u >> 10) & 2047u; atomicAdd(&h[idx], 1u); atomicAdd(&bs[idx], fix64(v.y)); }
        u = fkey(v.z); hi = u >> 21;
        if (hi > b1) { asum += fix64(v.z); acnt++; }
        else if (hi == b1) { unsigned idx = (u >> 10) & 2047u; atomicAdd(&h[idx], 1u); atomicAdd(&bs[idx], fix64(v.z)); }
        u = fkey(v.w); hi = u >> 21;
        if (hi > b1) { asum += fix64(v.w); acnt++; }
        else if (hi == b1) { unsigned idx = (u >> 10) & 2047u; atomicAdd(&h[idx], 1u); atomicAdd(&bs[idx], fix64(v.w)); }
    }
    // deterministic integer block reduction of the "above" partials
#pragma unroll
    for (int off = 32; off >= 1; off >>= 1) {
        asum += __shfl_down(asum, off);
        acnt += __shfl_down(acnt, off);
    }
    __shared__ unsigned long long wsum[4];
    __shared__ unsigned wcnt[4];
    int wid = threadIdx.x >> 6, lane = threadIdx.x & 63;
    if (lane == 0) { wsum[wid] = asum; wcnt[wid] = acnt; }
    __syncthreads();
    if (threadIdx.x == 0) {
        unsigned long long ts = wsum[0] + wsum[1] + wsum[2] + wsum[3];
        unsigned tc = wcnt[0] + wcnt[1] + wcnt[2] + wcnt[3];
        if (ts) atomicAdd(aboveSum, ts);
        if (tc) atomicAdd(aboveCnt, tc);
    }
    __syncthreads();
    for (int i = threadIdx.x; i < 2048; i += 256) {
        unsigned c = h[i];
        if (c) { atomicAdd(&h2g[i], c); atomicAdd(&bs2g[i], bs[i]); }
    }
}

// ---- last: find b2 in h2, include all bins >= b2, add above partials ----
__global__ __launch_bounds__(256) void k_last(const unsigned* __restrict__ h2,
                                              const unsigned long long* __restrict__ bs2,
                                              const unsigned long long* __restrict__ aboveSum,
                                              const unsigned* __restrict__ aboveCnt,
                                              const SelState* __restrict__ st,
                                              float* __restrict__ out) {
    __shared__ unsigned chunk[256];
    __shared__ unsigned b2sh;
    __shared__ unsigned long long wsum[4];
    __shared__ unsigned wcnt[4];
    int t = threadIdx.x;
    unsigned k = st->k1;
    if (t == 0) b2sh = 0u;  // fallback: include whole b1 bin

    unsigned local[8];
    unsigned lsum = 0;
#pragma unroll
    for (int j = 0; j < 8; ++j) { local[j] = h2[t * 8 + j]; lsum += local[j]; }
    chunk[t] = lsum;
    __syncthreads();
    for (int off = 1; off < 256; off <<= 1) {
        unsigned add = (t + off < 256) ? chunk[t + off] : 0u;
        __syncthreads();
        chunk[t] += add;
        __syncthreads();
    }
    unsigned cum = (t < 255) ? chunk[t + 1] : 0u;
#pragma unroll
    for (int j = 7; j >= 0; --j) {
        unsigned c = local[j];
        if (k > cum && k <= cum + c) b2sh = (unsigned)(t * 8 + j);
        cum += c;
    }
    __syncthreads();
    unsigned b2 = b2sh;

    unsigned long long s = 0ull;
    unsigned cnt = 0;
#pragma unroll
    for (int j = 0; j < 8; ++j) {
        unsigned bin = (unsigned)(t * 8 + j);
        if (bin >= b2) { s += bs2[bin]; cnt += local[j]; }
    }
#pragma unroll
    for (int off = 32; off >= 1; off >>= 1) {
        s += __shfl_down(s, off);
        cnt += __shfl_down(cnt, off);
    }
    int wid = t >> 6, lane = t & 63;
    if (lane == 0) { wsum[wid] = s; wcnt[wid] = cnt; }
    __syncthreads();
    if (t == 0) {
        unsigned long long ts = wsum[0] + wsum[1] + wsum[2] + wsum[3] + aboveSum[0];
        unsigned long long tc = (unsigned long long)(wcnt[0] + wcnt[1] + wcnt[2] + wcnt[3])
                              + (unsigned long long)aboveCnt[0];
        out[0] = (float)(((double)(long long)ts / FIX_SCALE) / (double)tc);
    }
}

extern "C" void kernel_launch(void* const* d_in, const int* in_sizes, int n_in,
                              void* d_out, int out_size, void* d_ws, size_t ws_size,
                              hipStream_t stream) {
    const float* pred = (const float*)d_in[0];
    const int* target = (const int*)d_in[1];
    const int* step = (const int*)d_in[2];
    float* out = (float*)d_out;

    char* ws = (char*)d_ws;
    const size_t LOSS_BYTES = (size_t)NPIX * 4;  // 16 MiB
    float* loss = (float*)ws;
    char* sb = ws + LOSS_BYTES;
    unsigned* h1 = (unsigned*)(sb);                            // 2048 u32 @ +0
    unsigned* h2 = (unsigned*)(sb + 8192);                     // 2048 u32 @ +8192
    unsigned long long* bs2 = (unsigned long long*)(sb + 16384);  // 2048 u64 @ +16384
    unsigned long long* aboveSum = (unsigned long long*)(sb + 32768);
    unsigned* aboveCnt = (unsigned*)(sb + 32776);
    SelState* st = (SelState*)(sb + 32784);

    hipMemsetAsync(sb, 0, 32780, stream);
    k_loss_hist<<<1024, 256, 0, stream>>>(pred, target, loss, h1);
    k_scan1<<<1, 256, 0, stream>>>(step, h1, st);
    k_hist2<<<1024, 256, 0, stream>>>(loss, st, h2, bs2, aboveSum, aboveCnt);
    k_last<<<1, 256, 0, stream>>>(h2, bs2, aboveSum, aboveCnt, st, out);
}